// Round 2
// baseline (466.377 us; speedup 1.0000x reference)
//
#include <hip/hip_runtime.h>
#include <hip/hip_bf16.h>
#include <stdint.h>

// Problem dims
#define DMODEL 1024
#define DHID   1024
#define NBATCH 8
#define LSEQ   2048
#define MROWS  (NBATCH * LSEQ)   // 16384
#define KCAT   2048              // [h | x] concat K
#define NCHUNK 32
#define CHUNK  64                // LSEQ / NCHUNK

typedef __attribute__((ext_vector_type(8))) short  short8;
typedef __attribute__((ext_vector_type(8))) __bf16 bf16x8;
typedef __attribute__((ext_vector_type(4))) float  f32x4;

__device__ __forceinline__ unsigned short f2bf(float f) {
  union { float f; unsigned int u; } v; v.f = f;
  unsigned int u = v.u;
  u += 0x7fffu + ((u >> 16) & 1u);   // round-to-nearest-even
  return (unsigned short)(u >> 16);
}

__device__ __forceinline__ float bf2f(unsigned short s) {
  union { unsigned int u; float f; } v; v.u = ((unsigned int)s) << 16;
  return v.f;
}

__device__ __forceinline__ float softplus_f(float x) {
  // log1p(exp(x)), stable form (== jax.nn.softplus)
  return fmaxf(x, 0.f) + log1pf(expf(-fabsf(x)));
}

__device__ __forceinline__ short8 pack8(float4 a, float4 b) {
  short8 o;
  o[0] = (short)f2bf(a.x); o[1] = (short)f2bf(a.y);
  o[2] = (short)f2bf(a.z); o[3] = (short)f2bf(a.w);
  o[4] = (short)f2bf(b.x); o[5] = (short)f2bf(b.y);
  o[6] = (short)f2bf(b.z); o[7] = (short)f2bf(b.w);
  return o;
}

// ---- cast kernels -------------------------------------------------------
// x [16384,1024] f32 -> bf16 into A2[:, 1024:2048] (row stride 2048)
__global__ __launch_bounds__(256)
void cast_x_kernel(const float* __restrict__ x, unsigned short* __restrict__ A2) {
  size_t i8 = ((size_t)blockIdx.x * 256 + threadIdx.x) * 8;
  size_t row = i8 >> 10;
  int col = (int)(i8 & 1023);
  const float4* p = (const float4*)(x + i8);
  float4 a = p[0], b = p[1];
  *(short8*)(A2 + row * (size_t)KCAT + 1024 + col) = pack8(a, b);
}

// W1 [2048,1024]: rows 0..1023 = dw, rows 1024..2047 = Bw
__global__ __launch_bounds__(256)
void cast_w1_kernel(const float* __restrict__ dw, const float* __restrict__ Bw,
                    unsigned short* __restrict__ W1) {
  size_t i8 = ((size_t)blockIdx.x * 256 + threadIdx.x) * 8;
  const float* src = (i8 < (size_t)1024 * 1024) ? (dw + i8) : (Bw + i8 - (size_t)1024 * 1024);
  const float4* p = (const float4*)src;
  *(short8*)(W1 + i8) = pack8(p[0], p[1]);
}

// W2 [1024,2048]: row d cols 0..1023 = Cw[d,:], cols 1024..2047 = Dw[d,:]
__global__ __launch_bounds__(256)
void cast_w2_kernel(const float* __restrict__ Cw, const float* __restrict__ Dw,
                    unsigned short* __restrict__ W2) {
  size_t i8 = ((size_t)blockIdx.x * 256 + threadIdx.x) * 8;
  size_t d = i8 >> 11;
  int c = (int)(i8 & 2047);
  const float* src = (c < 1024) ? (Cw + d * 1024 + c) : (Dw + d * 1024 + (c - 1024));
  const float4* p = (const float4*)src;
  *(short8*)(W2 + i8) = pack8(p[0], p[1]);
}

// ---- GEMM: C[M,N] = A[M,K] @ B[N,K]^T (+ optional per-col bias0+bias1) --
__device__ __forceinline__ void stage_tile(const unsigned short* g0, int ld,
                                           unsigned short* s0, int t, int lane) {
  // 128 rows x 32 cols bf16 tile = 8 KB, 256 threads x 2 x 16B
#pragma unroll
  for (int half = 0; half < 2; ++half) {
    int c = t + half * 256;
    const unsigned short* g = g0 + (size_t)(c >> 2) * ld + (c & 3) * 8;
    unsigned short* s = s0 + ((size_t)(t - lane) + half * 256) * 8; // wave-uniform base
    __builtin_amdgcn_global_load_lds(
        (const __attribute__((address_space(1))) unsigned int*)g,
        (__attribute__((address_space(3))) unsigned int*)s, 16, 0, 0);
  }
}

__global__ __launch_bounds__(256, 3)
void gemm_bt(const unsigned short* __restrict__ A, int lda,
             const unsigned short* __restrict__ B, int ldb,
             void* __restrict__ Cp, int ldc, int K, int out_bf16,
             const float* __restrict__ bias0, const float* __restrict__ bias1) {
  __shared__ __align__(16) unsigned short As[128 * 32];
  __shared__ __align__(16) unsigned short Bs[128 * 32];
  const int t = threadIdx.x;
  const int lane = t & 63, wave = t >> 6;
  const int quad = lane >> 4, l16 = lane & 15;
  const int m0 = blockIdx.y * 128, n0 = blockIdx.x * 128;
  const int wm = (wave & 1) * 64, wn = (wave >> 1) * 64;

  const unsigned short* Ab = A + (size_t)m0 * lda;
  const unsigned short* Bb = B + (size_t)n0 * ldb;

  f32x4 acc[4][4] = {};

  for (int k0 = 0; k0 < K; k0 += 32) {
    stage_tile(Ab + k0, lda, As, t, lane);
    stage_tile(Bb + k0, ldb, Bs, t, lane);
    __syncthreads();
    short8 af[4], bfr[4];
#pragma unroll
    for (int i = 0; i < 4; ++i)
      af[i] = *(const short8*)(As + ((size_t)(wm + i * 16 + l16)) * 32 + quad * 8);
#pragma unroll
    for (int j = 0; j < 4; ++j)
      bfr[j] = *(const short8*)(Bs + ((size_t)(wn + j * 16 + l16)) * 32 + quad * 8);
#pragma unroll
    for (int i = 0; i < 4; ++i)
#pragma unroll
      for (int j = 0; j < 4; ++j)
        acc[i][j] = __builtin_amdgcn_mfma_f32_16x16x32_bf16(
            __builtin_bit_cast(bf16x8, af[i]),
            __builtin_bit_cast(bf16x8, bfr[j]), acc[i][j], 0, 0, 0);
    __syncthreads();
  }

#pragma unroll
  for (int i = 0; i < 4; ++i) {
#pragma unroll
    for (int j = 0; j < 4; ++j) {
      int n = n0 + wn + j * 16 + l16;
      int mb = m0 + wm + i * 16 + quad * 4;
      float badd = 0.f;
      if (bias0) badd = bias0[n] + bias1[n];
      if (out_bf16) {
        unsigned short* C16 = (unsigned short*)Cp;
#pragma unroll
        for (int r = 0; r < 4; ++r)
          C16[(size_t)(mb + r) * ldc + n] = f2bf(acc[i][j][r] + badd);
      } else {
        float* C = (float*)Cp;
#pragma unroll
        for (int r = 0; r < 4; ++r)
          C[(size_t)(mb + r) * ldc + n] = acc[i][j][r] + badd;
      }
    }
  }
}

// ---- scan pass A: per-chunk carries (aprod, hend) -----------------------
// G1 is bf16 [16384, 2048]: col h = delta_pre[h], col 1024+h = B_pre[h]
__global__ __launch_bounds__(256)
void scan_carry_kernel(const unsigned short* __restrict__ G1, const float* __restrict__ Av,
                       const float* __restrict__ Bbv, const float* __restrict__ dbv,
                       float* __restrict__ apb, float* __restrict__ heb) {
  int t = blockIdx.x * 256 + threadIdx.x;
  int h = t & 1023, chunk = (t >> 10) & 31, b = t >> 15;
  float Ah = Av[h], Bbh = Bbv[h], dbh = dbv[h];
  const unsigned short* base = G1 + ((size_t)(b * LSEQ + chunk * CHUNK)) * KCAT + h;
  float hs = 0.f, sd = 0.f;
#pragma unroll 1
  for (int l = 0; l < CHUNK; l += 4) {
    float dp[4], bp[4];
#pragma unroll
    for (int j = 0; j < 4; ++j) {
      dp[j] = bf2f(base[(size_t)(l + j) * KCAT]);
      bp[j] = bf2f(base[(size_t)(l + j) * KCAT + 1024]);
    }
#pragma unroll
    for (int j = 0; j < 4; ++j) {
      float d = softplus_f(dp[j] + dbh);
      sd += d;
      float a = expf(d * Ah);
      hs = fmaf(a, hs, d * (bp[j] + Bbh));
    }
  }
  int ci = (b * NCHUNK + chunk) * 1024 + h;
  apb[ci] = expf(Ah * sd);   // product of per-step a over the chunk
  heb[ci] = hs;
}

// ---- scan pass B: compose carries across chunks -------------------------
__global__ __launch_bounds__(256)
void scan_comb_kernel(const float* __restrict__ apb, const float* __restrict__ heb,
                      float* __restrict__ Hc) {
  int t = blockIdx.x * 256 + threadIdx.x;   // 8192 = B*DH
  int h = t & 1023, b = t >> 10;
  float H = 0.f;
#pragma unroll
  for (int c = 0; c < NCHUNK; ++c) {
    int ci = (b * NCHUNK + c) * 1024 + h;
    Hc[ci] = H;                        // carry-in for chunk c
    H = fmaf(apb[ci], H, heb[ci]);
  }
}

// ---- scan pass C: recompute with carry, emit h as bf16 into A2[:,0:1024]
__global__ __launch_bounds__(256)
void scan_final_kernel(const unsigned short* __restrict__ G1, const float* __restrict__ Av,
                       const float* __restrict__ Bbv, const float* __restrict__ dbv,
                       const float* __restrict__ Hc, unsigned short* __restrict__ A2) {
  int t = blockIdx.x * 256 + threadIdx.x;
  int h = t & 1023, chunk = (t >> 10) & 31, b = t >> 15;
  float Ah = Av[h], Bbh = Bbv[h], dbh = dbv[h];
  const unsigned short* base = G1 + ((size_t)(b * LSEQ + chunk * CHUNK)) * KCAT + h;
  unsigned short* obase = A2 + ((size_t)(b * LSEQ + chunk * CHUNK)) * KCAT + h;
  float hs = Hc[(b * NCHUNK + chunk) * 1024 + h];
#pragma unroll 1
  for (int l = 0; l < CHUNK; l += 4) {
    float dp[4], bp[4];
#pragma unroll
    for (int j = 0; j < 4; ++j) {
      dp[j] = bf2f(base[(size_t)(l + j) * KCAT]);
      bp[j] = bf2f(base[(size_t)(l + j) * KCAT + 1024]);
    }
#pragma unroll
    for (int j = 0; j < 4; ++j) {
      float d = softplus_f(dp[j] + dbh);
      float a = expf(d * Ah);
      hs = fmaf(a, hs, d * (bp[j] + Bbh));
      obase[(size_t)(l + j) * KCAT] = f2bf(hs);
    }
  }
}

extern "C" void kernel_launch(void* const* d_in, const int* in_sizes, int n_in,
                              void* d_out, int out_size, void* d_ws, size_t ws_size,
                              hipStream_t stream) {
  const float* x  = (const float*)d_in[0];
  const float* Av = (const float*)d_in[1];
  const float* Bw = (const float*)d_in[2];
  const float* Bb = (const float*)d_in[3];
  const float* Cw = (const float*)d_in[4];
  const float* Cb = (const float*)d_in[5];
  const float* Dw = (const float*)d_in[6];
  const float* Db = (const float*)d_in[7];
  const float* dw = (const float*)d_in[8];
  const float* db = (const float*)d_in[9];
  float* out = (float*)d_out;

  // Workspace layout (bytes):
  //   A2  [16384,2048] bf16  = 64 MiB   ([h | x])
  //   G1  [16384,2048] bf16  = 64 MiB   ([delta_pre | B_pre])
  //   W1  [2048,1024]  bf16  =  4 MiB   ([dw;Bw])
  //   W2  [1024,2048]  bf16  =  4 MiB   ([Cw|Dw])
  //   apb/heb/Hc [8,32,1024] f32 = 3 MiB
  const size_t need = (size_t)MROWS * KCAT * 2 * 2
                    + (size_t)2048 * 1024 * 2 + (size_t)1024 * 2048 * 2
                    + (size_t)3 * NBATCH * NCHUNK * 1024 * 4;
  if (ws_size < need) return;  // refuse to scribble OOB; bench will report absmax fail

  char* w = (char*)d_ws;
  unsigned short* A2 = (unsigned short*)w; w += (size_t)MROWS * KCAT * 2;
  unsigned short* G1 = (unsigned short*)w; w += (size_t)MROWS * KCAT * 2;
  unsigned short* W1 = (unsigned short*)w; w += (size_t)2048 * 1024 * 2;
  unsigned short* W2 = (unsigned short*)w; w += (size_t)1024 * 2048 * 2;
  float* apb = (float*)w;                  w += (size_t)NBATCH * NCHUNK * 1024 * 4;
  float* heb = (float*)w;                  w += (size_t)NBATCH * NCHUNK * 1024 * 4;
  float* Hc  = (float*)w;                  w += (size_t)NBATCH * NCHUNK * 1024 * 4;

  // casts
  cast_x_kernel<<<(MROWS * 1024) / (256 * 8), 256, 0, stream>>>(x, A2);
  cast_w1_kernel<<<(2048 * 1024) / (256 * 8), 256, 0, stream>>>(dw, Bw, W1);
  cast_w2_kernel<<<(1024 * 2048) / (256 * 8), 256, 0, stream>>>(Cw, Dw, W2);

  // GEMM1: [delta_pre | B_pre] = x @ [dw;Bw]^T   (M=16384, N=2048, K=1024), bf16 out
  dim3 g1(KCAT / 128, MROWS / 128);
  gemm_bt<<<g1, 256, 0, stream>>>(A2 + 1024, KCAT, W1, 1024, G1, KCAT, 1024, 1,
                                  nullptr, nullptr);

  // chunked scan
  scan_carry_kernel<<<(NBATCH * NCHUNK * 1024) / 256, 256, 0, stream>>>(G1, Av, Bb, db, apb, heb);
  scan_comb_kernel<<<(NBATCH * 1024) / 256, 256, 0, stream>>>(apb, heb, Hc);
  scan_final_kernel<<<(NBATCH * NCHUNK * 1024) / 256, 256, 0, stream>>>(G1, Av, Bb, db, Hc, A2);

  // GEMM2: out = [h | x] @ [Cw|Dw]^T + Cb + Db   (M=16384, N=1024, K=2048), f32 out
  dim3 g2(DMODEL / 128, MROWS / 128);
  gemm_bt<<<g2, 256, 0, stream>>>(A2, KCAT, W2, KCAT, out, DMODEL, KCAT, 0, Cb, Db);
}

// Round 3
// 449.526 us; speedup vs baseline: 1.0375x; 1.0375x over previous
//
#include <hip/hip_runtime.h>
#include <hip/hip_bf16.h>
#include <stdint.h>

// Problem dims
#define DMODEL 1024
#define DHID   1024
#define NBATCH 8
#define LSEQ   2048
#define MROWS  (NBATCH * LSEQ)   // 16384
#define KCAT   2048              // [h | x] concat K
#define CH     32                // scan chunk length
#define NCH    64                // LSEQ / CH

typedef __attribute__((ext_vector_type(8))) short  short8;
typedef __attribute__((ext_vector_type(8))) __bf16 bf16x8;
typedef __attribute__((ext_vector_type(4))) float  f32x4;

__device__ __forceinline__ unsigned short f2bf(float f) {
  union { float f; unsigned int u; } v; v.f = f;
  unsigned int u = v.u;
  u += 0x7fffu + ((u >> 16) & 1u);   // round-to-nearest-even
  return (unsigned short)(u >> 16);
}

__device__ __forceinline__ float bf2f(unsigned short s) {
  union { unsigned int u; float f; } v; v.u = ((unsigned int)s) << 16;
  return v.f;
}

__device__ __forceinline__ float softplus_f(float x) {
  return fmaxf(x, 0.f) + log1pf(expf(-fabsf(x)));   // == jax.nn.softplus
}

__device__ __forceinline__ short8 pack8(float4 a, float4 b) {
  short8 o;
  o[0] = (short)f2bf(a.x); o[1] = (short)f2bf(a.y);
  o[2] = (short)f2bf(a.z); o[3] = (short)f2bf(a.w);
  o[4] = (short)f2bf(b.x); o[5] = (short)f2bf(b.y);
  o[6] = (short)f2bf(b.z); o[7] = (short)f2bf(b.w);
  return o;
}

// ---- cast kernels -------------------------------------------------------
// x [16384,1024] f32 -> bf16 into A2[:, 1024:2048] (row stride 2048)
__global__ __launch_bounds__(256)
void cast_x_kernel(const float* __restrict__ x, unsigned short* __restrict__ A2) {
  size_t i8 = ((size_t)blockIdx.x * 256 + threadIdx.x) * 8;
  size_t row = i8 >> 10;
  int col = (int)(i8 & 1023);
  const float4* p = (const float4*)(x + i8);
  *(short8*)(A2 + row * (size_t)KCAT + 1024 + col) = pack8(p[0], p[1]);
}

// W1 [2048,1024] = [dw;Bw]; W2 [1024,2048] = [Cw|Dw], in one kernel
__global__ __launch_bounds__(256)
void cast_w_kernel(const float* __restrict__ dw, const float* __restrict__ Bw,
                   const float* __restrict__ Cw, const float* __restrict__ Dw,
                   unsigned short* __restrict__ W1, unsigned short* __restrict__ W2) {
  const size_t M1 = (size_t)1024 * 1024;
  size_t i8 = ((size_t)blockIdx.x * 256 + threadIdx.x) * 8;
  if (i8 < 2 * M1) {                 // W1
    const float* src = (i8 < M1) ? (dw + i8) : (Bw + i8 - M1);
    const float4* p = (const float4*)src;
    *(short8*)(W1 + i8) = pack8(p[0], p[1]);
  } else {                           // W2
    size_t k = i8 - 2 * M1;
    size_t d = k >> 11;
    int c = (int)(k & 2047);
    const float* src = (c < 1024) ? (Cw + d * 1024 + c) : (Dw + d * 1024 + (c - 1024));
    const float4* p = (const float4*)src;
    *(short8*)(W2 + k) = pack8(p[0], p[1]);
  }
}

// ---- GEMM: C[M,N] = A[M,K] @ B[N,K]^T (+ optional per-col bias0+bias1) --
__device__ __forceinline__ void stage_tile(const unsigned short* g0, int ld,
                                           unsigned short* s0, int t, int lane) {
#pragma unroll
  for (int half = 0; half < 2; ++half) {
    int c = t + half * 256;
    const unsigned short* g = g0 + (size_t)(c >> 2) * ld + (c & 3) * 8;
    unsigned short* s = s0 + ((size_t)(t - lane) + half * 256) * 8; // wave-uniform base
    __builtin_amdgcn_global_load_lds(
        (const __attribute__((address_space(1))) unsigned int*)g,
        (__attribute__((address_space(3))) unsigned int*)s, 16, 0, 0);
  }
}

__global__ __launch_bounds__(256, 4)
void gemm_bt(const unsigned short* __restrict__ A, int lda,
             const unsigned short* __restrict__ B, int ldb,
             void* __restrict__ Cp, int ldc, int K, int out_bf16,
             const float* __restrict__ bias0, const float* __restrict__ bias1) {
  __shared__ __align__(16) unsigned short As[128 * 32];
  __shared__ __align__(16) unsigned short Bs[128 * 32];
  const int t = threadIdx.x;
  const int lane = t & 63, wave = t >> 6;
  const int quad = lane >> 4, l16 = lane & 15;

  // XCD-aware swizzle: each XCD (bid%8) owns a contiguous M-band, iterated
  // N-fastest so the 4 MB weight matrix stays resident in that XCD's L2.
  const int Nt = gridDim.x, Mt = gridDim.y;
  int bid = blockIdx.y * Nt + blockIdx.x;
  int xcd = bid & 7;
  int slot = bid >> 3;
  int lm = slot / Nt;
  int ln = slot - lm * Nt;
  const int m0 = (xcd * (Mt >> 3) + lm) * 128;
  const int n0 = ln * 128;

  const int wm = (wave & 1) * 64, wn = (wave >> 1) * 64;

  const unsigned short* Ab = A + (size_t)m0 * lda;
  const unsigned short* Bb = B + (size_t)n0 * ldb;

  f32x4 acc[4][4] = {};

  for (int k0 = 0; k0 < K; k0 += 32) {
    stage_tile(Ab + k0, lda, As, t, lane);
    stage_tile(Bb + k0, ldb, Bs, t, lane);
    __syncthreads();
    short8 af[4], bfr[4];
#pragma unroll
    for (int i = 0; i < 4; ++i)
      af[i] = *(const short8*)(As + ((size_t)(wm + i * 16 + l16)) * 32 + quad * 8);
#pragma unroll
    for (int j = 0; j < 4; ++j)
      bfr[j] = *(const short8*)(Bs + ((size_t)(wn + j * 16 + l16)) * 32 + quad * 8);
#pragma unroll
    for (int i = 0; i < 4; ++i)
#pragma unroll
      for (int j = 0; j < 4; ++j)
        acc[i][j] = __builtin_amdgcn_mfma_f32_16x16x32_bf16(
            __builtin_bit_cast(bf16x8, af[i]),
            __builtin_bit_cast(bf16x8, bfr[j]), acc[i][j], 0, 0, 0);
    __syncthreads();
  }

#pragma unroll
  for (int i = 0; i < 4; ++i) {
#pragma unroll
    for (int j = 0; j < 4; ++j) {
      int n = n0 + wn + j * 16 + l16;
      int mb = m0 + wm + i * 16 + quad * 4;
      float badd = 0.f;
      if (bias0) badd = bias0[n] + bias1[n];
      if (out_bf16) {
        unsigned short* C16 = (unsigned short*)Cp;
#pragma unroll
        for (int r = 0; r < 4; ++r)
          C16[(size_t)(mb + r) * ldc + n] = f2bf(acc[i][j][r] + badd);
      } else {
        float* C = (float*)Cp;
#pragma unroll
        for (int r = 0; r < 4; ++r)
          C[(size_t)(mb + r) * ldc + n] = acc[i][j][r] + badd;
      }
    }
  }
}

// ---- scan pass A: per-chunk carries, 8 channels/thread, short8 loads ----
// G1 bf16 [16384,2048]: col h = delta_pre, col 1024+h = B_pre
// carr layout: [b][h][c] float2 {aprod, hend} — contiguous in c for pass B
__global__ __launch_bounds__(256)
void scan_carry_kernel(const unsigned short* __restrict__ G1,
                       const float* __restrict__ Av, const float* __restrict__ Bbv,
                       const float* __restrict__ dbv, float2* __restrict__ carr) {
  int t = blockIdx.x * 256 + threadIdx.x;      // 65536 = 8 * 64 * 128
  int ho = t & 127, chunk = (t >> 7) & (NCH - 1), b = t >> 13;
  int h0 = ho << 3;
  float4 A0 = *(const float4*)(Av + h0),  A1 = *(const float4*)(Av + h0 + 4);
  float4 B0 = *(const float4*)(Bbv + h0), B1 = *(const float4*)(Bbv + h0 + 4);
  float4 D0 = *(const float4*)(dbv + h0), D1 = *(const float4*)(dbv + h0 + 4);
  float Ah[8]  = {A0.x, A0.y, A0.z, A0.w, A1.x, A1.y, A1.z, A1.w};
  float Bbh[8] = {B0.x, B0.y, B0.z, B0.w, B1.x, B1.y, B1.z, B1.w};
  float dbh[8] = {D0.x, D0.y, D0.z, D0.w, D1.x, D1.y, D1.z, D1.w};
  const unsigned short* base = G1 + ((size_t)(b * LSEQ + chunk * CH)) * KCAT + h0;
  float hs[8] = {}, sd[8] = {};
#pragma unroll 4
  for (int l = 0; l < CH; ++l) {
    short8 dp = *(const short8*)(base + (size_t)l * KCAT);
    short8 bp = *(const short8*)(base + (size_t)l * KCAT + 1024);
#pragma unroll
    for (int j = 0; j < 8; ++j) {
      float d = softplus_f(bf2f((unsigned short)dp[j]) + dbh[j]);
      sd[j] += d;
      float a = expf(d * Ah[j]);
      hs[j] = fmaf(a, hs[j], d * (bf2f((unsigned short)bp[j]) + Bbh[j]));
    }
  }
#pragma unroll
  for (int j = 0; j < 8; ++j) {
    size_t ci = ((size_t)(b * 1024 + h0 + j) << 6) + chunk;   // *NCH
    carr[ci] = make_float2(expf(Ah[j] * sd[j]), hs[j]);
  }
}

// ---- scan pass B: compose carries (contiguous float2 stream per thread) -
__global__ __launch_bounds__(256)
void scan_comb_kernel(const float2* __restrict__ carr, float* __restrict__ Hc) {
  int t = blockIdx.x * 256 + threadIdx.x;   // 8192 = B*DH
  size_t rb = (size_t)t << 6;               // *NCH
  float H = 0.f;
#pragma unroll
  for (int c = 0; c < NCH; ++c) {
    float2 ah = carr[rb + c];
    Hc[rb + c] = H;                          // carry-in for chunk c
    H = fmaf(ah.x, H, ah.y);
  }
}

// ---- scan pass C: recompute with carry, emit h bf16 into A2[:,0:1024] ---
__global__ __launch_bounds__(256)
void scan_final_kernel(const unsigned short* __restrict__ G1,
                       const float* __restrict__ Av, const float* __restrict__ Bbv,
                       const float* __restrict__ dbv, const float* __restrict__ Hc,
                       unsigned short* __restrict__ A2) {
  int t = blockIdx.x * 256 + threadIdx.x;
  int ho = t & 127, chunk = (t >> 7) & (NCH - 1), b = t >> 13;
  int h0 = ho << 3;
  float4 A0 = *(const float4*)(Av + h0),  A1 = *(const float4*)(Av + h0 + 4);
  float4 B0 = *(const float4*)(Bbv + h0), B1 = *(const float4*)(Bbv + h0 + 4);
  float4 D0 = *(const float4*)(dbv + h0), D1 = *(const float4*)(dbv + h0 + 4);
  float Ah[8]  = {A0.x, A0.y, A0.z, A0.w, A1.x, A1.y, A1.z, A1.w};
  float Bbh[8] = {B0.x, B0.y, B0.z, B0.w, B1.x, B1.y, B1.z, B1.w};
  float dbh[8] = {D0.x, D0.y, D0.z, D0.w, D1.x, D1.y, D1.z, D1.w};
  const unsigned short* base = G1 + ((size_t)(b * LSEQ + chunk * CH)) * KCAT + h0;
  unsigned short* obase = A2 + ((size_t)(b * LSEQ + chunk * CH)) * KCAT + h0;
  float hs[8];
#pragma unroll
  for (int j = 0; j < 8; ++j)
    hs[j] = Hc[((size_t)(b * 1024 + h0 + j) << 6) + chunk];
#pragma unroll 4
  for (int l = 0; l < CH; ++l) {
    short8 dp = *(const short8*)(base + (size_t)l * KCAT);
    short8 bp = *(const short8*)(base + (size_t)l * KCAT + 1024);
    short8 o;
#pragma unroll
    for (int j = 0; j < 8; ++j) {
      float d = softplus_f(bf2f((unsigned short)dp[j]) + dbh[j]);
      float a = expf(d * Ah[j]);
      hs[j] = fmaf(a, hs[j], d * (bf2f((unsigned short)bp[j]) + Bbh[j]));
      o[j] = (short)f2bf(hs[j]);
    }
    *(short8*)(obase + (size_t)l * KCAT) = o;
  }
}

extern "C" void kernel_launch(void* const* d_in, const int* in_sizes, int n_in,
                              void* d_out, int out_size, void* d_ws, size_t ws_size,
                              hipStream_t stream) {
  const float* x  = (const float*)d_in[0];
  const float* Av = (const float*)d_in[1];
  const float* Bw = (const float*)d_in[2];
  const float* Bb = (const float*)d_in[3];
  const float* Cw = (const float*)d_in[4];
  const float* Cb = (const float*)d_in[5];
  const float* Dw = (const float*)d_in[6];
  const float* Db = (const float*)d_in[7];
  const float* dw = (const float*)d_in[8];
  const float* db = (const float*)d_in[9];
  float* out = (float*)d_out;

  // Workspace:
  //   A2 [16384,2048] bf16 = 64 MiB   ([h | x])
  //   G1 [16384,2048] bf16 = 64 MiB   ([delta_pre | B_pre])
  //   W1 [2048,1024]  bf16 =  4 MiB   ([dw;Bw]; reused as carr after GEMM1)
  //   W2 [1024,2048]  bf16 =  4 MiB   ([Cw|Dw])
  //   Hc [8,1024,64]  f32  =  2 MiB
  const size_t sz_big = (size_t)MROWS * KCAT * 2;      // 64 MiB
  const size_t sz_w   = (size_t)2048 * 1024 * 2;       //  4 MiB
  const size_t sz_hc  = (size_t)NBATCH * 1024 * NCH * 4; // 2 MiB
  const size_t need = 2 * sz_big + 2 * sz_w + sz_hc;   // ~138 MiB (< round-2's 139)
  if (ws_size < need) return;

  char* w = (char*)d_ws;
  unsigned short* A2 = (unsigned short*)w; w += sz_big;
  unsigned short* G1 = (unsigned short*)w; w += sz_big;
  unsigned short* W1 = (unsigned short*)w; w += sz_w;
  unsigned short* W2 = (unsigned short*)w; w += sz_w;
  float* Hc = (float*)w;                   w += sz_hc;
  float2* carr = (float2*)W1;  // W1 dead after GEMM1; carr = 4 MiB exactly

  // casts
  cast_x_kernel<<<(MROWS * 1024) / (256 * 8), 256, 0, stream>>>(x, A2);
  cast_w_kernel<<<(4 * 1024 * 1024) / (256 * 8), 256, 0, stream>>>(dw, Bw, Cw, Dw, W1, W2);

  // GEMM1: [delta_pre | B_pre] = x @ [dw;Bw]^T  (M=16384,N=2048,K=1024), bf16 out
  dim3 g1(KCAT / 128, MROWS / 128);
  gemm_bt<<<g1, 256, 0, stream>>>(A2 + 1024, KCAT, W1, 1024, G1, KCAT, 1024, 1,
                                  nullptr, nullptr);

  // chunked scan: h[l] = a[l]*h[l-1] + b[l]
  scan_carry_kernel<<<(NBATCH * NCH * 128) / 256, 256, 0, stream>>>(G1, Av, Bb, db, carr);
  scan_comb_kernel<<<(NBATCH * 1024) / 256, 256, 0, stream>>>(carr, Hc);
  scan_final_kernel<<<(NBATCH * NCH * 128) / 256, 256, 0, stream>>>(G1, Av, Bb, db, Hc, A2);

  // GEMM2: out = [h | x] @ [Cw|Dw]^T + Cb + Db  (M=16384,N=1024,K=2048), f32 out
  dim3 g2(DMODEL / 128, MROWS / 128);
  gemm_bt<<<g2, 256, 0, stream>>>(A2, KCAT, W2, KCAT, out, DMODEL, KCAT, 0, Cb, Db);
}

// Round 4
// 398.339 us; speedup vs baseline: 1.1708x; 1.1285x over previous
//
#include <hip/hip_runtime.h>
#include <hip/hip_bf16.h>
#include <stdint.h>

// Problem dims
#define DMODEL 1024
#define DHID   1024
#define NBATCH 8
#define LSEQ   2048
#define MROWS  (NBATCH * LSEQ)   // 16384
#define KCAT   2048              // [h | x] concat K
#define CH     32                // scan chunk length
#define NCH    64                // LSEQ / CH
#define BH     (NBATCH * DHID)   // 8192

typedef __attribute__((ext_vector_type(8))) short  short8;
typedef __attribute__((ext_vector_type(8))) __bf16 bf16x8;
typedef __attribute__((ext_vector_type(4))) float  f32x4;

__device__ __forceinline__ unsigned short f2bf(float f) {
  union { float f; unsigned int u; } v; v.f = f;
  unsigned int u = v.u;
  u += 0x7fffu + ((u >> 16) & 1u);   // round-to-nearest-even
  return (unsigned short)(u >> 16);
}

__device__ __forceinline__ float bf2f(unsigned short s) {
  union { unsigned int u; float f; } v; v.u = ((unsigned int)s) << 16;
  return v.f;
}

__device__ __forceinline__ float softplus_f(float x) {
  return fmaxf(x, 0.f) + log1pf(expf(-fabsf(x)));   // == jax.nn.softplus
}

__device__ __forceinline__ short8 pack8(float4 a, float4 b) {
  short8 o;
  o[0] = (short)f2bf(a.x); o[1] = (short)f2bf(a.y);
  o[2] = (short)f2bf(a.z); o[3] = (short)f2bf(a.w);
  o[4] = (short)f2bf(b.x); o[5] = (short)f2bf(b.y);
  o[6] = (short)f2bf(b.z); o[7] = (short)f2bf(b.w);
  return o;
}

// ---- one cast kernel: x -> A2[:,1024:], W1 (paired dw/Bw), W2 ([Cw|Dw]) --
__global__ __launch_bounds__(256)
void cast_all_kernel(const float* __restrict__ x,
                     const float* __restrict__ dw, const float* __restrict__ Bw,
                     const float* __restrict__ Cw, const float* __restrict__ Dw,
                     unsigned short* __restrict__ A2,
                     unsigned short* __restrict__ W1, unsigned short* __restrict__ W2) {
  const size_t MX = (size_t)MROWS * 1024;       // 16M: x
  const size_t M1 = (size_t)2048 * 1024;        // 2M:  W1
  size_t i8 = ((size_t)blockIdx.x * 256 + threadIdx.x) * 8;
  if (i8 < MX) {
    size_t row = i8 >> 10; int col = (int)(i8 & 1023);
    const float4* p = (const float4*)(x + i8);
    *(short8*)(A2 + row * (size_t)KCAT + 1024 + col) = pack8(p[0], p[1]);
  } else if (i8 < MX + M1) {
    size_t k = i8 - MX;
    size_t row = k >> 10; int col = (int)(k & 1023);
    size_t h = row >> 1;
    const float* src = (row & 1) ? (Bw + h * 1024 + col) : (dw + h * 1024 + col);
    const float4* p = (const float4*)src;
    *(short8*)(W1 + k) = pack8(p[0], p[1]);
  } else {
    size_t k = i8 - MX - M1;
    size_t d = k >> 11; int c = (int)(k & 2047);
    const float* src = (c < 1024) ? (Cw + d * 1024 + c) : (Dw + d * 1024 + (c - 1024));
    const float4* p = (const float4*)src;
    *(short8*)(W2 + k) = pack8(p[0], p[1]);
  }
}

// ---- GEMM: C[M,N] = A[M,K] @ B[N,K]^T ------------------------------------
// mode 0: f32 out + bias0+bias1
// mode 2: fused SSM-pre epilogue: B rows paired (2h=dw,2h+1=Bw); emits
//         G[:,h]=softplus(dpre+db[h]) bf16, G[:,1024+h]=d*(bpre+Bb[h]) bf16
__device__ __forceinline__ void stage_tile(const unsigned short* g0, int ld,
                                           unsigned short* s0, int t, int lane) {
#pragma unroll
  for (int half = 0; half < 2; ++half) {
    int c = t + half * 256;
    const unsigned short* g = g0 + (size_t)(c >> 2) * ld + (c & 3) * 8;
    unsigned short* s = s0 + ((size_t)(t - lane) + half * 256) * 8; // wave-uniform base
    __builtin_amdgcn_global_load_lds(
        (const __attribute__((address_space(1))) unsigned int*)g,
        (__attribute__((address_space(3))) unsigned int*)s, 16, 0, 0);
  }
}

__global__ __launch_bounds__(256, 4)
void gemm_bt(const unsigned short* __restrict__ A, int lda,
             const unsigned short* __restrict__ B, int ldb,
             void* __restrict__ Cp, int ldc, int K, int mode,
             const float* __restrict__ bias0, const float* __restrict__ bias1) {
  __shared__ __align__(16) unsigned short As[128 * 32];
  __shared__ __align__(16) unsigned short Bs[128 * 32];
  const int t = threadIdx.x;
  const int lane = t & 63, wave = t >> 6;
  const int quad = lane >> 4, l16 = lane & 15;

  // XCD-aware swizzle: each XCD (bid%8) owns a contiguous M-band, N-fastest,
  // so the weight matrix stays resident in that XCD's 4 MB L2.
  const int Nt = gridDim.x, Mt = gridDim.y;
  int bid = blockIdx.y * Nt + blockIdx.x;
  int xcd = bid & 7;
  int slot = bid >> 3;
  int lm = slot / Nt;
  int ln = slot - lm * Nt;
  const int m0 = (xcd * (Mt >> 3) + lm) * 128;
  const int n0 = ln * 128;

  const int wm = (wave & 1) * 64, wn = (wave >> 1) * 64;

  const unsigned short* Ab = A + (size_t)m0 * lda;
  const unsigned short* Bb = B + (size_t)n0 * ldb;

  f32x4 acc[4][4] = {};

  for (int k0 = 0; k0 < K; k0 += 32) {
    stage_tile(Ab + k0, lda, As, t, lane);
    stage_tile(Bb + k0, ldb, Bs, t, lane);
    __syncthreads();
    short8 af[4], bfr[4];
#pragma unroll
    for (int i = 0; i < 4; ++i)
      af[i] = *(const short8*)(As + ((size_t)(wm + i * 16 + l16)) * 32 + quad * 8);
#pragma unroll
    for (int j = 0; j < 4; ++j)
      bfr[j] = *(const short8*)(Bs + ((size_t)(wn + j * 16 + l16)) * 32 + quad * 8);
#pragma unroll
    for (int i = 0; i < 4; ++i)
#pragma unroll
      for (int j = 0; j < 4; ++j)
        acc[i][j] = __builtin_amdgcn_mfma_f32_16x16x32_bf16(
            __builtin_bit_cast(bf16x8, af[i]),
            __builtin_bit_cast(bf16x8, bfr[j]), acc[i][j], 0, 0, 0);
    __syncthreads();
  }

  if (mode == 0) {
    float* C = (float*)Cp;
#pragma unroll
    for (int i = 0; i < 4; ++i)
#pragma unroll
      for (int j = 0; j < 4; ++j) {
        int n = n0 + wn + j * 16 + l16;
        int mb = m0 + wm + i * 16 + quad * 4;
        float badd = bias0[n] + bias1[n];
#pragma unroll
        for (int r = 0; r < 4; ++r)
          C[(size_t)(mb + r) * ldc + n] = acc[i][j][r] + badd;
      }
  } else {
    // fused SSM-pre epilogue (ldc = KCAT, out bf16 halves)
    unsigned short* G = (unsigned short*)Cp;
    const int even = !(lane & 1);
#pragma unroll
    for (int j = 0; j < 4; ++j) {
      int n = n0 + wn + j * 16 + l16;
      int h = n >> 1;
      float dbh = bias0[h], Bbh = bias1[h];
#pragma unroll
      for (int i = 0; i < 4; ++i) {
        int mb = m0 + wm + i * 16 + quad * 4;
#pragma unroll
        for (int r = 0; r < 4; ++r) {
          float mine = acc[i][j][r];
          float other = __shfl_xor(mine, 1, 64);
          float dpre = even ? mine : other;
          float bpre = even ? other : mine;
          float d = softplus_f(dpre + dbh);
          float bb = d * (bpre + Bbh);
          size_t off = (size_t)(mb + r) * KCAT + h + (even ? 0 : 1024);
          G[off] = f2bf(even ? d : bb);
        }
      }
    }
  }
}

// ---- scan pass A: per-chunk carries, 8 channels/thread ------------------
// G1 bf16 [16384,2048]: col h = d (softplus'ed), col 1024+h = bb
// carr layout: [c][b*1024+h] float2 {aprod, hend} — lane-contiguous always
__global__ __launch_bounds__(256)
void scan_carry_kernel(const unsigned short* __restrict__ G1,
                       const float* __restrict__ Av, float2* __restrict__ carr) {
  int t = blockIdx.x * 256 + threadIdx.x;      // 65536 = 8 * 64 * 128
  int ho = t & 127, chunk = (t >> 7) & (NCH - 1), b = t >> 13;
  int h0 = ho << 3;
  float4 A0 = *(const float4*)(Av + h0), A1 = *(const float4*)(Av + h0 + 4);
  float Ah[8] = {A0.x, A0.y, A0.z, A0.w, A1.x, A1.y, A1.z, A1.w};
  const unsigned short* base = G1 + ((size_t)(b * LSEQ + chunk * CH)) * KCAT + h0;
  float hs[8] = {}, sd[8] = {};
#pragma unroll 4
  for (int l = 0; l < CH; ++l) {
    short8 dp = *(const short8*)(base + (size_t)l * KCAT);
    short8 bp = *(const short8*)(base + (size_t)l * KCAT + 1024);
#pragma unroll
    for (int j = 0; j < 8; ++j) {
      float d = bf2f((unsigned short)dp[j]);
      sd[j] += d;
      float a = __expf(d * Ah[j]);
      hs[j] = fmaf(a, hs[j], bf2f((unsigned short)bp[j]));
    }
  }
  float2* cb = carr + (size_t)chunk * BH + b * 1024 + h0;
#pragma unroll
  for (int j = 0; j < 8; ++j)
    cb[j] = make_float2(__expf(Ah[j] * sd[j]), hs[j]);
}

// ---- scan pass B: compose carries (lane-contiguous) ---------------------
__global__ __launch_bounds__(256)
void scan_comb_kernel(const float2* __restrict__ carr, float* __restrict__ Hc) {
  int t = blockIdx.x * 256 + threadIdx.x;   // 8192 = B*DH
  float H = 0.f;
#pragma unroll
  for (int c = 0; c < NCH; ++c) {
    float2 ah = carr[(size_t)c * BH + t];
    Hc[(size_t)c * BH + t] = H;              // carry-in for chunk c
    H = fmaf(ah.x, H, ah.y);
  }
}

// ---- scan pass C: recompute with carry, emit h bf16 into A2[:,0:1024] ---
__global__ __launch_bounds__(256)
void scan_final_kernel(const unsigned short* __restrict__ G1,
                       const float* __restrict__ Av, const float* __restrict__ Hc,
                       unsigned short* __restrict__ A2) {
  int t = blockIdx.x * 256 + threadIdx.x;
  int ho = t & 127, chunk = (t >> 7) & (NCH - 1), b = t >> 13;
  int h0 = ho << 3;
  float4 A0 = *(const float4*)(Av + h0), A1 = *(const float4*)(Av + h0 + 4);
  float Ah[8] = {A0.x, A0.y, A0.z, A0.w, A1.x, A1.y, A1.z, A1.w};
  const unsigned short* base = G1 + ((size_t)(b * LSEQ + chunk * CH)) * KCAT + h0;
  unsigned short* obase = A2 + ((size_t)(b * LSEQ + chunk * CH)) * KCAT + h0;
  const float* hb = Hc + (size_t)chunk * BH + b * 1024 + h0;
  float hs[8];
#pragma unroll
  for (int j = 0; j < 8; ++j) hs[j] = hb[j];
#pragma unroll 4
  for (int l = 0; l < CH; ++l) {
    short8 dp = *(const short8*)(base + (size_t)l * KCAT);
    short8 bp = *(const short8*)(base + (size_t)l * KCAT + 1024);
    short8 o;
#pragma unroll
    for (int j = 0; j < 8; ++j) {
      float d = bf2f((unsigned short)dp[j]);
      float a = __expf(d * Ah[j]);
      hs[j] = fmaf(a, hs[j], bf2f((unsigned short)bp[j]));
      o[j] = (short)f2bf(hs[j]);
    }
    *(short8*)(obase + (size_t)l * KCAT) = o;
  }
}

extern "C" void kernel_launch(void* const* d_in, const int* in_sizes, int n_in,
                              void* d_out, int out_size, void* d_ws, size_t ws_size,
                              hipStream_t stream) {
  const float* x  = (const float*)d_in[0];
  const float* Av = (const float*)d_in[1];
  const float* Bw = (const float*)d_in[2];
  const float* Bb = (const float*)d_in[3];
  const float* Cw = (const float*)d_in[4];
  const float* Cb = (const float*)d_in[5];
  const float* Dw = (const float*)d_in[6];
  const float* Db = (const float*)d_in[7];
  const float* dw = (const float*)d_in[8];
  const float* db = (const float*)d_in[9];
  float* out = (float*)d_out;

  // Workspace:
  //   A2 [16384,2048] bf16 = 64 MiB ([h | x])
  //   G1 [16384,2048] bf16 = 64 MiB ([d | bb], post-pointwise)
  //   W1 [2048,1024]  bf16 =  4 MiB (paired dw/Bw; reused as carr after GEMM1)
  //   W2 [1024,2048]  bf16 =  4 MiB ([Cw|Dw])
  //   Hc [64,8192]    f32  =  2 MiB
  const size_t sz_big = (size_t)MROWS * KCAT * 2;
  const size_t sz_w   = (size_t)2048 * 1024 * 2;
  const size_t sz_hc  = (size_t)NCH * BH * 4;
  const size_t need = 2 * sz_big + 2 * sz_w + sz_hc;
  if (ws_size < need) return;

  char* w = (char*)d_ws;
  unsigned short* A2 = (unsigned short*)w; w += sz_big;
  unsigned short* G1 = (unsigned short*)w; w += sz_big;
  unsigned short* W1 = (unsigned short*)w; w += sz_w;
  unsigned short* W2 = (unsigned short*)w; w += sz_w;
  float* Hc = (float*)w;                   w += sz_hc;
  float2* carr = (float2*)W1;  // W1 dead after GEMM1; carr = 4 MiB exactly

  // cast everything (x, W1-paired, W2) in one launch
  const size_t cast_elems = (size_t)MROWS * 1024 + 2 * (size_t)2048 * 1024;
  cast_all_kernel<<<(int)(cast_elems / (256 * 8)), 256, 0, stream>>>(
      x, dw, Bw, Cw, Dw, A2, W1, W2);

  // GEMM1 + fused pointwise: G1 = [d | bb]  (M=16384,N=2048,K=1024)
  dim3 g1(KCAT / 128, MROWS / 128);
  gemm_bt<<<g1, 256, 0, stream>>>(A2 + 1024, KCAT, W1, 1024, G1, KCAT, 1024, 2,
                                  db, Bb);

  // chunked scan: h[l] = a[l]*h[l-1] + bb[l]
  scan_carry_kernel<<<(NBATCH * NCH * 128) / 256, 256, 0, stream>>>(G1, Av, carr);
  scan_comb_kernel<<<BH / 256, 256, 0, stream>>>(carr, Hc);
  scan_final_kernel<<<(NBATCH * NCH * 128) / 256, 256, 0, stream>>>(G1, Av, Hc, A2);

  // GEMM2: out = [h | x] @ [Cw|Dw]^T + Cb + Db  (M=16384,N=1024,K=2048), f32 out
  dim3 g2(DMODEL / 128, MROWS / 128);
  gemm_bt<<<g2, 256, 0, stream>>>(A2, KCAT, W2, KCAT, out, DMODEL, KCAT, 0, Cb, Db);
}

// Round 5
// 391.034 us; speedup vs baseline: 1.1927x; 1.0187x over previous
//
#include <hip/hip_runtime.h>
#include <hip/hip_bf16.h>
#include <stdint.h>

// Problem dims
#define DMODEL 1024
#define DHID   1024
#define NBATCH 8
#define LSEQ   2048
#define MROWS  (NBATCH * LSEQ)   // 16384
#define KCAT   2048              // [h | x] concat K
#define CH     32                // scan chunk length
#define NCH    64                // LSEQ / CH
#define BH     (NBATCH * DHID)   // 8192

typedef __attribute__((ext_vector_type(8))) short  short8;
typedef __attribute__((ext_vector_type(8))) __bf16 bf16x8;
typedef __attribute__((ext_vector_type(4))) float  f32x4;

__device__ __forceinline__ unsigned short f2bf(float f) {
  union { float f; unsigned int u; } v; v.f = f;
  unsigned int u = v.u;
  u += 0x7fffu + ((u >> 16) & 1u);   // round-to-nearest-even
  return (unsigned short)(u >> 16);
}

__device__ __forceinline__ float bf2f(unsigned short s) {
  union { unsigned int u; float f; } v; v.u = ((unsigned int)s) << 16;
  return v.f;
}

__device__ __forceinline__ float softplus_f(float x) {
  return fmaxf(x, 0.f) + log1pf(expf(-fabsf(x)));   // == jax.nn.softplus
}

__device__ __forceinline__ short8 pack8(float4 a, float4 b) {
  short8 o;
  o[0] = (short)f2bf(a.x); o[1] = (short)f2bf(a.y);
  o[2] = (short)f2bf(a.z); o[3] = (short)f2bf(a.w);
  o[4] = (short)f2bf(b.x); o[5] = (short)f2bf(b.y);
  o[6] = (short)f2bf(b.z); o[7] = (short)f2bf(b.w);
  return o;
}

// ---- one cast kernel: x -> A2[:,1024:], W1=[dw;Bw], W2=[Cw|Dw] -----------
__global__ __launch_bounds__(256)
void cast_all_kernel(const float* __restrict__ x,
                     const float* __restrict__ dw, const float* __restrict__ Bw,
                     const float* __restrict__ Cw, const float* __restrict__ Dw,
                     unsigned short* __restrict__ A2,
                     unsigned short* __restrict__ W1, unsigned short* __restrict__ W2) {
  const size_t MX = (size_t)MROWS * 1024;       // 16M: x
  const size_t M1 = (size_t)1024 * 1024;        // 1M
  size_t i8 = ((size_t)blockIdx.x * 256 + threadIdx.x) * 8;
  if (i8 < MX) {
    size_t row = i8 >> 10; int col = (int)(i8 & 1023);
    const float4* p = (const float4*)(x + i8);
    *(short8*)(A2 + row * (size_t)KCAT + 1024 + col) = pack8(p[0], p[1]);
  } else if (i8 < MX + 2 * M1) {                // W1 rows 0..1023=dw, 1024..2047=Bw
    size_t k = i8 - MX;
    const float* src = (k < M1) ? (dw + k) : (Bw + k - M1);
    const float4* p = (const float4*)src;
    *(short8*)(W1 + k) = pack8(p[0], p[1]);
  } else {                                      // W2 row d: [Cw[d,:] | Dw[d,:]]
    size_t k = i8 - MX - 2 * M1;
    size_t d = k >> 11; int c = (int)(k & 2047);
    const float* src = (c < 1024) ? (Cw + d * 1024 + c) : (Dw + d * 1024 + (c - 1024));
    const float4* p = (const float4*)src;
    *(short8*)(W2 + k) = pack8(p[0], p[1]);
  }
}

// ---- GEMM: C[M,N] = A[M,K] @ B[N,K]^T ------------------------------------
// mode 0: f32 out, += bias0[n]+bias1[n];  mode 1: bf16 out, no bias
__device__ __forceinline__ void stage_tile(const unsigned short* g0, int ld,
                                           unsigned short* s0, int t, int lane) {
#pragma unroll
  for (int half = 0; half < 2; ++half) {
    int c = t + half * 256;
    const unsigned short* g = g0 + (size_t)(c >> 2) * ld + (c & 3) * 8;
    unsigned short* s = s0 + ((size_t)(t - lane) + half * 256) * 8; // wave-uniform base
    __builtin_amdgcn_global_load_lds(
        (const __attribute__((address_space(1))) unsigned int*)g,
        (__attribute__((address_space(3))) unsigned int*)s, 16, 0, 0);
  }
}

__global__ __launch_bounds__(256, 4)
void gemm_bt(const unsigned short* __restrict__ A, int lda,
             const unsigned short* __restrict__ B, int ldb,
             void* __restrict__ Cp, int ldc, int K, int mode,
             const float* __restrict__ bias0, const float* __restrict__ bias1) {
  __shared__ __align__(16) unsigned short As[128 * 32];
  __shared__ __align__(16) unsigned short Bs[128 * 32];
  const int t = threadIdx.x;
  const int lane = t & 63, wave = t >> 6;
  const int quad = lane >> 4, l16 = lane & 15;

  // XCD-aware swizzle: each XCD (bid%8) owns a contiguous M-band, N-fastest,
  // so the weight matrix stays resident in that XCD's 4 MB L2.
  const int Nt = gridDim.x, Mt = gridDim.y;
  int bid = blockIdx.y * Nt + blockIdx.x;
  int xcd = bid & 7;
  int slot = bid >> 3;
  int lm = slot / Nt;
  int ln = slot - lm * Nt;
  const int m0 = (xcd * (Mt >> 3) + lm) * 128;
  const int n0 = ln * 128;

  const int wm = (wave & 1) * 64, wn = (wave >> 1) * 64;

  const unsigned short* Ab = A + (size_t)m0 * lda;
  const unsigned short* Bb = B + (size_t)n0 * ldb;

  f32x4 acc[4][4] = {};

  for (int k0 = 0; k0 < K; k0 += 32) {
    stage_tile(Ab + k0, lda, As, t, lane);
    stage_tile(Bb + k0, ldb, Bs, t, lane);
    __syncthreads();
    short8 af[4], bfr[4];
#pragma unroll
    for (int i = 0; i < 4; ++i)
      af[i] = *(const short8*)(As + ((size_t)(wm + i * 16 + l16)) * 32 + quad * 8);
#pragma unroll
    for (int j = 0; j < 4; ++j)
      bfr[j] = *(const short8*)(Bs + ((size_t)(wn + j * 16 + l16)) * 32 + quad * 8);
#pragma unroll
    for (int i = 0; i < 4; ++i)
#pragma unroll
      for (int j = 0; j < 4; ++j)
        acc[i][j] = __builtin_amdgcn_mfma_f32_16x16x32_bf16(
            __builtin_bit_cast(bf16x8, af[i]),
            __builtin_bit_cast(bf16x8, bfr[j]), acc[i][j], 0, 0, 0);
    __syncthreads();
  }

  if (mode == 0) {
    float* C = (float*)Cp;
#pragma unroll
    for (int i = 0; i < 4; ++i)
#pragma unroll
      for (int j = 0; j < 4; ++j) {
        int n = n0 + wn + j * 16 + l16;
        int mb = m0 + wm + i * 16 + quad * 4;
        float badd = bias0[n] + bias1[n];
#pragma unroll
        for (int r = 0; r < 4; ++r)
          C[(size_t)(mb + r) * ldc + n] = acc[i][j][r] + badd;
      }
  } else {
    unsigned short* C16 = (unsigned short*)Cp;
#pragma unroll
    for (int i = 0; i < 4; ++i)
#pragma unroll
      for (int j = 0; j < 4; ++j) {
        int n = n0 + wn + j * 16 + l16;
        int mb = m0 + wm + i * 16 + quad * 4;
#pragma unroll
        for (int r = 0; r < 4; ++r)
          C16[(size_t)(mb + r) * ldc + n] = f2bf(acc[i][j][r]);
      }
  }
}

// ---- scan pass A: pointwise transform (in-place) + per-chunk carries ----
// In:  G1 bf16 [16384,2048] = [dpre | bpre]
// Out: G1 overwritten with [d | bb], d=softplus(dpre+db), bb=d*(bpre+Bb);
//      carr[c][b*1024+h] = {exp(A*sum d), h_end of chunk from h=0}
// Carries computed from the bf16-ROUNDED d/bb so pass C's recurrence matches.
__global__ __launch_bounds__(256)
void scan_carry_kernel(unsigned short* __restrict__ G1,
                       const float* __restrict__ Av, const float* __restrict__ Bbv,
                       const float* __restrict__ dbv, float2* __restrict__ carr) {
  int t = blockIdx.x * 256 + threadIdx.x;      // 65536 = 8 * 64 * 128
  int ho = t & 127, chunk = (t >> 7) & (NCH - 1), b = t >> 13;
  int h0 = ho << 3;
  float4 A0 = *(const float4*)(Av + h0),  A1 = *(const float4*)(Av + h0 + 4);
  float4 B0 = *(const float4*)(Bbv + h0), B1 = *(const float4*)(Bbv + h0 + 4);
  float4 D0 = *(const float4*)(dbv + h0), D1 = *(const float4*)(dbv + h0 + 4);
  float Ah[8]  = {A0.x, A0.y, A0.z, A0.w, A1.x, A1.y, A1.z, A1.w};
  float Bbh[8] = {B0.x, B0.y, B0.z, B0.w, B1.x, B1.y, B1.z, B1.w};
  float dbh[8] = {D0.x, D0.y, D0.z, D0.w, D1.x, D1.y, D1.z, D1.w};
  unsigned short* base = G1 + ((size_t)(b * LSEQ + chunk * CH)) * KCAT + h0;
  float hs[8] = {}, sd[8] = {};
#pragma unroll 2
  for (int l = 0; l < CH; ++l) {
    short8 dp = *(const short8*)(base + (size_t)l * KCAT);
    short8 bp = *(const short8*)(base + (size_t)l * KCAT + 1024);
    short8 dq, bq;
#pragma unroll
    for (int j = 0; j < 8; ++j) {
      float d = softplus_f(bf2f((unsigned short)dp[j]) + dbh[j]);
      unsigned short dr = f2bf(d);
      float drf = bf2f(dr);
      float bb = drf * (bf2f((unsigned short)bp[j]) + Bbh[j]);
      unsigned short br = f2bf(bb);
      sd[j] += drf;
      float a = __expf(drf * Ah[j]);
      hs[j] = fmaf(a, hs[j], bf2f(br));
      dq[j] = (short)dr; bq[j] = (short)br;
    }
    *(short8*)(base + (size_t)l * KCAT) = dq;
    *(short8*)(base + (size_t)l * KCAT + 1024) = bq;
  }
  float2* cb = carr + (size_t)chunk * BH + b * 1024 + h0;
#pragma unroll
  for (int j = 0; j < 8; ++j)
    cb[j] = make_float2(__expf(Ah[j] * sd[j]), hs[j]);
}

// ---- scan pass B: compose carries (lane-contiguous) ---------------------
__global__ __launch_bounds__(256)
void scan_comb_kernel(const float2* __restrict__ carr, float* __restrict__ Hc) {
  int t = blockIdx.x * 256 + threadIdx.x;   // 8192 = B*DH
  float H = 0.f;
#pragma unroll
  for (int c = 0; c < NCH; ++c) {
    float2 ah = carr[(size_t)c * BH + t];
    Hc[(size_t)c * BH + t] = H;              // carry-in for chunk c
    H = fmaf(ah.x, H, ah.y);
  }
}

// ---- scan pass C: recompute with carry, emit h bf16 into A2[:,0:1024] ---
__global__ __launch_bounds__(256)
void scan_final_kernel(const unsigned short* __restrict__ G1,
                       const float* __restrict__ Av, const float* __restrict__ Hc,
                       unsigned short* __restrict__ A2) {
  int t = blockIdx.x * 256 + threadIdx.x;
  int ho = t & 127, chunk = (t >> 7) & (NCH - 1), b = t >> 13;
  int h0 = ho << 3;
  float4 A0 = *(const float4*)(Av + h0), A1 = *(const float4*)(Av + h0 + 4);
  float Ah[8] = {A0.x, A0.y, A0.z, A0.w, A1.x, A1.y, A1.z, A1.w};
  const unsigned short* base = G1 + ((size_t)(b * LSEQ + chunk * CH)) * KCAT + h0;
  unsigned short* obase = A2 + ((size_t)(b * LSEQ + chunk * CH)) * KCAT + h0;
  const float* hb = Hc + (size_t)chunk * BH + b * 1024 + h0;
  float hs[8];
#pragma unroll
  for (int j = 0; j < 8; ++j) hs[j] = hb[j];
#pragma unroll 4
  for (int l = 0; l < CH; ++l) {
    short8 dp = *(const short8*)(base + (size_t)l * KCAT);
    short8 bp = *(const short8*)(base + (size_t)l * KCAT + 1024);
    short8 o;
#pragma unroll
    for (int j = 0; j < 8; ++j) {
      float d = bf2f((unsigned short)dp[j]);
      float a = __expf(d * Ah[j]);
      hs[j] = fmaf(a, hs[j], bf2f((unsigned short)bp[j]));
      o[j] = (short)f2bf(hs[j]);
    }
    *(short8*)(obase + (size_t)l * KCAT) = o;
  }
}

extern "C" void kernel_launch(void* const* d_in, const int* in_sizes, int n_in,
                              void* d_out, int out_size, void* d_ws, size_t ws_size,
                              hipStream_t stream) {
  const float* x  = (const float*)d_in[0];
  const float* Av = (const float*)d_in[1];
  const float* Bw = (const float*)d_in[2];
  const float* Bb = (const float*)d_in[3];
  const float* Cw = (const float*)d_in[4];
  const float* Cb = (const float*)d_in[5];
  const float* Dw = (const float*)d_in[6];
  const float* Db = (const float*)d_in[7];
  const float* dw = (const float*)d_in[8];
  const float* db = (const float*)d_in[9];
  float* out = (float*)d_out;

  // Workspace:
  //   A2 [16384,2048] bf16 = 64 MiB ([h | x])
  //   G1 [16384,2048] bf16 = 64 MiB ([dpre|bpre] -> in-place [d|bb])
  //   W1 [2048,1024]  bf16 =  4 MiB ([dw;Bw]; reused as carr after GEMM1)
  //   W2 [1024,2048]  bf16 =  4 MiB ([Cw|Dw])
  //   Hc [64,8192]    f32  =  2 MiB
  const size_t sz_big = (size_t)MROWS * KCAT * 2;
  const size_t sz_w   = (size_t)2048 * 1024 * 2;
  const size_t sz_hc  = (size_t)NCH * BH * 4;
  const size_t need = 2 * sz_big + 2 * sz_w + sz_hc;
  if (ws_size < need) return;

  char* w = (char*)d_ws;
  unsigned short* A2 = (unsigned short*)w; w += sz_big;
  unsigned short* G1 = (unsigned short*)w; w += sz_big;
  unsigned short* W1 = (unsigned short*)w; w += sz_w;
  unsigned short* W2 = (unsigned short*)w; w += sz_w;
  float* Hc = (float*)w;                   w += sz_hc;
  float2* carr = (float2*)W1;  // W1 dead after GEMM1; carr = 4 MiB exactly

  // cast everything (x, W1, W2) in one launch
  const size_t cast_elems = (size_t)MROWS * 1024 + 2 * (size_t)2048 * 1024;
  cast_all_kernel<<<(int)(cast_elems / (256 * 8)), 256, 0, stream>>>(
      x, dw, Bw, Cw, Dw, A2, W1, W2);

  // GEMM1: G1 = x @ [dw;Bw]^T -> [dpre | bpre]  (M=16384,N=2048,K=1024), bf16
  dim3 g1(KCAT / 128, MROWS / 128);
  gemm_bt<<<g1, 256, 0, stream>>>(A2 + 1024, KCAT, W1, 1024, G1, KCAT, 1024, 1,
                                  nullptr, nullptr);

  // chunked scan: pointwise (softplus once, in-place) + carries, compose, final
  scan_carry_kernel<<<(NBATCH * NCH * 128) / 256, 256, 0, stream>>>(G1, Av, Bb, db, carr);
  scan_comb_kernel<<<BH / 256, 256, 0, stream>>>(carr, Hc);
  scan_final_kernel<<<(NBATCH * NCH * 128) / 256, 256, 0, stream>>>(G1, Av, Hc, A2);

  // GEMM2: out = [h | x] @ [Cw|Dw]^T + Cb + Db  (M=16384,N=1024,K=2048), f32
  dim3 g2(DMODEL / 128, MROWS / 128);
  gemm_bt<<<g2, 256, 0, stream>>>(A2, KCAT, W2, KCAT, out, DMODEL, KCAT, 0, Cb, Db);
}

// Round 6
// 372.023 us; speedup vs baseline: 1.2536x; 1.0511x over previous
//
#include <hip/hip_runtime.h>
#include <hip/hip_bf16.h>
#include <stdint.h>

// Problem dims
#define DMODEL 1024
#define DHID   1024
#define NBATCH 8
#define LSEQ   2048
#define MROWS  (NBATCH * LSEQ)   // 16384
#define KCAT   2048              // [h | x] concat K
#define CH     32                // scan chunk length
#define NCH    64                // LSEQ / CH
#define BH     (NBATCH * DHID)   // 8192
#define CPT    4                 // channels per scan thread

typedef __attribute__((ext_vector_type(8))) short  short8;
typedef __attribute__((ext_vector_type(4))) short  s16x4;
typedef __attribute__((ext_vector_type(8))) __bf16 bf16x8;
typedef __attribute__((ext_vector_type(4))) float  f32x4;

__device__ __forceinline__ unsigned short f2bf(float f) {
  union { float f; unsigned int u; } v; v.f = f;
  unsigned int u = v.u;
  u += 0x7fffu + ((u >> 16) & 1u);   // round-to-nearest-even
  return (unsigned short)(u >> 16);
}

__device__ __forceinline__ float bf2f(unsigned short s) {
  union { unsigned int u; float f; } v; v.u = ((unsigned int)s) << 16;
  return v.f;
}

__device__ __forceinline__ float softplus_f(float x) {
  return fmaxf(x, 0.f) + log1pf(expf(-fabsf(x)));   // == jax.nn.softplus
}

__device__ __forceinline__ short8 pack8(float4 a, float4 b) {
  short8 o;
  o[0] = (short)f2bf(a.x); o[1] = (short)f2bf(a.y);
  o[2] = (short)f2bf(a.z); o[3] = (short)f2bf(a.w);
  o[4] = (short)f2bf(b.x); o[5] = (short)f2bf(b.y);
  o[6] = (short)f2bf(b.z); o[7] = (short)f2bf(b.w);
  return o;
}

// ---- one cast kernel: x -> A2[:,1024:], W1=[dw;Bw], W2=[Cw|Dw] -----------
__global__ __launch_bounds__(256)
void cast_all_kernel(const float* __restrict__ x,
                     const float* __restrict__ dw, const float* __restrict__ Bw,
                     const float* __restrict__ Cw, const float* __restrict__ Dw,
                     unsigned short* __restrict__ A2,
                     unsigned short* __restrict__ W1, unsigned short* __restrict__ W2) {
  const size_t MX = (size_t)MROWS * 1024;       // 16M: x
  const size_t M1 = (size_t)1024 * 1024;        // 1M
  size_t i8 = ((size_t)blockIdx.x * 256 + threadIdx.x) * 8;
  if (i8 < MX) {
    size_t row = i8 >> 10; int col = (int)(i8 & 1023);
    const float4* p = (const float4*)(x + i8);
    *(short8*)(A2 + row * (size_t)KCAT + 1024 + col) = pack8(p[0], p[1]);
  } else if (i8 < MX + 2 * M1) {                // W1 rows 0..1023=dw, 1024..2047=Bw
    size_t k = i8 - MX;
    const float* src = (k < M1) ? (dw + k) : (Bw + k - M1);
    const float4* p = (const float4*)src;
    *(short8*)(W1 + k) = pack8(p[0], p[1]);
  } else {                                      // W2 row d: [Cw[d,:] | Dw[d,:]]
    size_t k = i8 - MX - 2 * M1;
    size_t d = k >> 11; int c = (int)(k & 2047);
    const float* src = (c < 1024) ? (Cw + d * 1024 + c) : (Dw + d * 1024 + (c - 1024));
    const float4* p = (const float4*)src;
    *(short8*)(W2 + k) = pack8(p[0], p[1]);
  }
}

// ---- GEMM: C[M,N] = A[M,K] @ B[N,K]^T ------------------------------------
// mode 0: f32 out, += bias0[n]+bias1[n];  mode 1: bf16 out, no bias
__device__ __forceinline__ void stage_tile(const unsigned short* g0, int ld,
                                           unsigned short* s0, int t, int lane) {
#pragma unroll
  for (int half = 0; half < 2; ++half) {
    int c = t + half * 256;
    const unsigned short* g = g0 + (size_t)(c >> 2) * ld + (c & 3) * 8;
    unsigned short* s = s0 + ((size_t)(t - lane) + half * 256) * 8; // wave-uniform base
    __builtin_amdgcn_global_load_lds(
        (const __attribute__((address_space(1))) unsigned int*)g,
        (__attribute__((address_space(3))) unsigned int*)s, 16, 0, 0);
  }
}

__global__ __launch_bounds__(256, 4)
void gemm_bt(const unsigned short* __restrict__ A, int lda,
             const unsigned short* __restrict__ B, int ldb,
             void* __restrict__ Cp, int ldc, int K, int mode,
             const float* __restrict__ bias0, const float* __restrict__ bias1) {
  __shared__ __align__(16) unsigned short As[128 * 32];
  __shared__ __align__(16) unsigned short Bs[128 * 32];
  const int t = threadIdx.x;
  const int lane = t & 63, wave = t >> 6;
  const int quad = lane >> 4, l16 = lane & 15;

  // XCD-aware swizzle: each XCD (bid%8) owns a contiguous M-band, N-fastest,
  // so the weight matrix stays resident in that XCD's 4 MB L2.
  const int Nt = gridDim.x, Mt = gridDim.y;
  int bid = blockIdx.y * Nt + blockIdx.x;
  int xcd = bid & 7;
  int slot = bid >> 3;
  int lm = slot / Nt;
  int ln = slot - lm * Nt;
  const int m0 = (xcd * (Mt >> 3) + lm) * 128;
  const int n0 = ln * 128;

  const int wm = (wave & 1) * 64, wn = (wave >> 1) * 64;

  const unsigned short* Ab = A + (size_t)m0 * lda;
  const unsigned short* Bb = B + (size_t)n0 * ldb;

  f32x4 acc[4][4] = {};

  for (int k0 = 0; k0 < K; k0 += 32) {
    stage_tile(Ab + k0, lda, As, t, lane);
    stage_tile(Bb + k0, ldb, Bs, t, lane);
    __syncthreads();
    short8 af[4], bfr[4];
#pragma unroll
    for (int i = 0; i < 4; ++i)
      af[i] = *(const short8*)(As + ((size_t)(wm + i * 16 + l16)) * 32 + quad * 8);
#pragma unroll
    for (int j = 0; j < 4; ++j)
      bfr[j] = *(const short8*)(Bs + ((size_t)(wn + j * 16 + l16)) * 32 + quad * 8);
#pragma unroll
    for (int i = 0; i < 4; ++i)
#pragma unroll
      for (int j = 0; j < 4; ++j)
        acc[i][j] = __builtin_amdgcn_mfma_f32_16x16x32_bf16(
            __builtin_bit_cast(bf16x8, af[i]),
            __builtin_bit_cast(bf16x8, bfr[j]), acc[i][j], 0, 0, 0);
    __syncthreads();
  }

  if (mode == 0) {
    float* C = (float*)Cp;
#pragma unroll
    for (int i = 0; i < 4; ++i)
#pragma unroll
      for (int j = 0; j < 4; ++j) {
        int n = n0 + wn + j * 16 + l16;
        int mb = m0 + wm + i * 16 + quad * 4;
        float badd = bias0[n] + bias1[n];
#pragma unroll
        for (int r = 0; r < 4; ++r)
          C[(size_t)(mb + r) * ldc + n] = acc[i][j][r] + badd;
      }
  } else {
    unsigned short* C16 = (unsigned short*)Cp;
#pragma unroll
    for (int i = 0; i < 4; ++i)
#pragma unroll
      for (int j = 0; j < 4; ++j) {
        int n = n0 + wn + j * 16 + l16;
        int mb = m0 + wm + i * 16 + quad * 4;
#pragma unroll
        for (int r = 0; r < 4; ++r)
          C16[(size_t)(mb + r) * ldc + n] = f2bf(acc[i][j][r]);
      }
  }
}

// ---- scan pass A: pointwise (in-place) + per-chunk carries --------------
// 4 channels/thread, 131072 threads = 8 waves/CU; loads software-pipelined.
// In:  G1 bf16 [16384,2048] = [dpre | bpre]
// Out: G1 = [d | bb]; carr[c][b*1024+h] = {exp(A*sum d), chunk h_end from 0}
__global__ __launch_bounds__(256)
void scan_carry_kernel(unsigned short* __restrict__ G1,
                       const float* __restrict__ Av, const float* __restrict__ Bbv,
                       const float* __restrict__ dbv, float2* __restrict__ carr) {
  int t = blockIdx.x * 256 + threadIdx.x;      // 131072 = 8 * 64 * 256
  int ho = t & 255, chunk = (t >> 8) & (NCH - 1), b = t >> 14;
  int h0 = ho << 2;
  float4 A0 = *(const float4*)(Av + h0);
  float4 B0 = *(const float4*)(Bbv + h0);
  float4 D0 = *(const float4*)(dbv + h0);
  float Ah[4]  = {A0.x, A0.y, A0.z, A0.w};
  float Bbh[4] = {B0.x, B0.y, B0.z, B0.w};
  float dbh[4] = {D0.x, D0.y, D0.z, D0.w};
  unsigned short* base = G1 + ((size_t)(b * LSEQ + chunk * CH)) * KCAT + h0;
  float hs[4] = {}, sd[4] = {};
  s16x4 dp = *(const s16x4*)(base);
  s16x4 bp = *(const s16x4*)(base + 1024);
#pragma unroll 4
  for (int l = 0; l < CH; ++l) {
    s16x4 dpn = dp, bpn = bp;
    if (l + 1 < CH) {                           // prefetch next step
      dpn = *(const s16x4*)(base + (size_t)(l + 1) * KCAT);
      bpn = *(const s16x4*)(base + (size_t)(l + 1) * KCAT + 1024);
    }
    s16x4 dq, bq;
#pragma unroll
    for (int j = 0; j < 4; ++j) {
      float d = softplus_f(bf2f((unsigned short)dp[j]) + dbh[j]);
      unsigned short dr = f2bf(d);
      float drf = bf2f(dr);
      float bb = drf * (bf2f((unsigned short)bp[j]) + Bbh[j]);
      unsigned short br = f2bf(bb);
      sd[j] += drf;
      float a = __expf(drf * Ah[j]);
      hs[j] = fmaf(a, hs[j], bf2f(br));
      dq[j] = (short)dr; bq[j] = (short)br;
    }
    *(s16x4*)(base + (size_t)l * KCAT) = dq;
    *(s16x4*)(base + (size_t)l * KCAT + 1024) = bq;
    dp = dpn; bp = bpn;
  }
  float2* cb = carr + (size_t)chunk * BH + b * 1024 + h0;
#pragma unroll
  for (int j = 0; j < 4; ++j)
    cb[j] = make_float2(__expf(Ah[j] * sd[j]), hs[j]);
}

// ---- scan pass B: compose carries (lane-contiguous) ---------------------
__global__ __launch_bounds__(256)
void scan_comb_kernel(const float2* __restrict__ carr, float* __restrict__ Hc) {
  int t = blockIdx.x * 256 + threadIdx.x;   // 8192 = B*DH
  float H = 0.f;
#pragma unroll
  for (int c = 0; c < NCH; ++c) {
    float2 ah = carr[(size_t)c * BH + t];
    Hc[(size_t)c * BH + t] = H;              // carry-in for chunk c
    H = fmaf(ah.x, H, ah.y);
  }
}

// ---- scan pass C: recompute with carry, emit h bf16 into A2[:,0:1024] ---
__global__ __launch_bounds__(256)
void scan_final_kernel(const unsigned short* __restrict__ G1,
                       const float* __restrict__ Av, const float* __restrict__ Hc,
                       unsigned short* __restrict__ A2) {
  int t = blockIdx.x * 256 + threadIdx.x;      // 131072
  int ho = t & 255, chunk = (t >> 8) & (NCH - 1), b = t >> 14;
  int h0 = ho << 2;
  float4 A0 = *(const float4*)(Av + h0);
  float Ah[4] = {A0.x, A0.y, A0.z, A0.w};
  const unsigned short* base = G1 + ((size_t)(b * LSEQ + chunk * CH)) * KCAT + h0;
  unsigned short* obase = A2 + ((size_t)(b * LSEQ + chunk * CH)) * KCAT + h0;
  const float* hb = Hc + (size_t)chunk * BH + b * 1024 + h0;
  float hs[4];
#pragma unroll
  for (int j = 0; j < 4; ++j) hs[j] = hb[j];
  s16x4 dp = *(const s16x4*)(base);
  s16x4 bp = *(const s16x4*)(base + 1024);
#pragma unroll 4
  for (int l = 0; l < CH; ++l) {
    s16x4 dpn = dp, bpn = bp;
    if (l + 1 < CH) {                           // prefetch next step
      dpn = *(const s16x4*)(base + (size_t)(l + 1) * KCAT);
      bpn = *(const s16x4*)(base + (size_t)(l + 1) * KCAT + 1024);
    }
    s16x4 o;
#pragma unroll
    for (int j = 0; j < 4; ++j) {
      float d = bf2f((unsigned short)dp[j]);
      float a = __expf(d * Ah[j]);
      hs[j] = fmaf(a, hs[j], bf2f((unsigned short)bp[j]));
      o[j] = (short)f2bf(hs[j]);
    }
    *(s16x4*)(obase + (size_t)l * KCAT) = o;
    dp = dpn; bp = bpn;
  }
}

extern "C" void kernel_launch(void* const* d_in, const int* in_sizes, int n_in,
                              void* d_out, int out_size, void* d_ws, size_t ws_size,
                              hipStream_t stream) {
  const float* x  = (const float*)d_in[0];
  const float* Av = (const float*)d_in[1];
  const float* Bw = (const float*)d_in[2];
  const float* Bb = (const float*)d_in[3];
  const float* Cw = (const float*)d_in[4];
  const float* Cb = (const float*)d_in[5];
  const float* Dw = (const float*)d_in[6];
  const float* Db = (const float*)d_in[7];
  const float* dw = (const float*)d_in[8];
  const float* db = (const float*)d_in[9];
  float* out = (float*)d_out;

  // Workspace (138 MiB, same as proven rounds):
  //   A2 [16384,2048] bf16 = 64 MiB ([h | x])
  //   G1 [16384,2048] bf16 = 64 MiB ([dpre|bpre] -> in-place [d|bb])
  //   W1 [2048,1024]  bf16 =  4 MiB ([dw;Bw]; reused as carr after GEMM1)
  //   W2 [1024,2048]  bf16 =  4 MiB ([Cw|Dw])
  //   Hc [64,8192]    f32  =  2 MiB
  const size_t sz_big = (size_t)MROWS * KCAT * 2;
  const size_t sz_w   = (size_t)2048 * 1024 * 2;
  const size_t sz_hc  = (size_t)NCH * BH * 4;
  const size_t need = 2 * sz_big + 2 * sz_w + sz_hc;
  if (ws_size < need) return;

  char* w = (char*)d_ws;
  unsigned short* A2 = (unsigned short*)w; w += sz_big;
  unsigned short* G1 = (unsigned short*)w; w += sz_big;
  unsigned short* W1 = (unsigned short*)w; w += sz_w;
  unsigned short* W2 = (unsigned short*)w; w += sz_w;
  float* Hc = (float*)w;                   w += sz_hc;
  float2* carr = (float2*)W1;  // W1 dead after GEMM1; carr = NCH*BH*8 = 4 MiB exactly

  // cast everything (x, W1, W2) in one launch
  const size_t cast_elems = (size_t)MROWS * 1024 + 2 * (size_t)2048 * 1024;
  cast_all_kernel<<<(int)(cast_elems / (256 * 8)), 256, 0, stream>>>(
      x, dw, Bw, Cw, Dw, A2, W1, W2);

  // GEMM1: G1 = x @ [dw;Bw]^T -> [dpre | bpre]  (M=16384,N=2048,K=1024), bf16
  dim3 g1(KCAT / 128, MROWS / 128);
  gemm_bt<<<g1, 256, 0, stream>>>(A2 + 1024, KCAT, W1, 1024, G1, KCAT, 1024, 1,
                                  nullptr, nullptr);

  // chunked scan: pointwise (softplus once, in-place) + carries, compose, final
  scan_carry_kernel<<<(NBATCH * NCH * (DHID / CPT)) / 256, 256, 0, stream>>>(
      G1, Av, Bb, db, carr);
  scan_comb_kernel<<<BH / 256, 256, 0, stream>>>(carr, Hc);
  scan_final_kernel<<<(NBATCH * NCH * (DHID / CPT)) / 256, 256, 0, stream>>>(
      G1, Av, Hc, A2);

  // GEMM2: out = [h | x] @ [Cw|Dw]^T + Cb + Db  (M=16384,N=1024,K=2048), f32
  dim3 g2(DMODEL / 128, MROWS / 128);
  gemm_bt<<<g2, 256, 0, stream>>>(A2, KCAT, W2, KCAT, out, DMODEL, KCAT, 0, Cb, Db);
}